// Round 6
// baseline (274.041 us; speedup 1.0000x reference)
//
#include <hip/hip_runtime.h>

#define BB 4
#define NN 512
#define FF 64

typedef __attribute__((ext_vector_type(8))) short short8v;   // 8 bf16 = 4 VGPR
typedef __attribute__((ext_vector_type(4))) float f32x4;

__device__ __forceinline__ float silu_f(float v) {
  // raw v_rcp_f32 instead of IEEE divide chain; ~1 ulp, fine at our threshold
  return v * __builtin_amdgcn_rcpf(1.0f + __expf(-v));
}
__device__ __forceinline__ unsigned short f2bf(float f) {
  unsigned int u = __float_as_uint(f);
  unsigned int r = (u + 0x7FFFu + ((u >> 16) & 1u)) >> 16;   // RNE (prep kernel only)
  return (unsigned short)r;
}
__device__ __forceinline__ float bf2f(unsigned short s) {
  return __uint_as_float(((unsigned int)s) << 16);
}
// packed f32x2 -> bf16x2 (RNE), low16 = a
__device__ __forceinline__ unsigned cvt_pk_bf16(float a, float b) {
  unsigned r;
  asm("v_cvt_pk_bf16_f32 %0, %1, %2" : "=v"(r) : "v"(a), "v"(b));
  return r;
}

// act LDS addressing: [j][k] bf16 rows of 128B, 16B slots XOR-swizzled by j.
#define AIDX(j, k) ((((j) << 6)) | (((((k) >> 3) ^ ((j) & 7))) << 3) | ((k) & 7))

// ---------------- prep kernel ----------------
// wg 0..63: G[b,j,o] = h_j @ We1[0:64];  Base[b,i,o] = be1 + h_i @ We1[64:128]
// wg 64   : split-transpose weights -> Wt{2,3,4}{hi,lo}[out][in] bf16
__global__ void sake_prep(const float* __restrict__ h, const float* __restrict__ We1,
                          const float* __restrict__ be1, const float* __restrict__ We2,
                          const float* __restrict__ Wc1, const float* __restrict__ Wc2,
                          float* __restrict__ G, float* __restrict__ Base,
                          unsigned short* __restrict__ w2h, unsigned short* __restrict__ w2l,
                          unsigned short* __restrict__ w3h, unsigned short* __restrict__ w3l,
                          unsigned short* __restrict__ w4h, unsigned short* __restrict__ w4l)
{
  const int wg = (int)blockIdx.x, tid = (int)threadIdx.x;
  if (wg < 64) {
    __shared__ float sH[32][64];
    const int r0 = wg * 32;
    for (int idx = tid; idx < 2048; idx += 256) sH[idx >> 6][idx & 63] = h[r0 * 64 + idx];
    __syncthreads();
    const int rl = tid >> 3;          // row 0..31
    const int o0 = (tid & 7) * 8;     // 8 outputs
    float aG[8], aB[8];
    #pragma unroll
    for (int o = 0; o < 8; ++o) { aG[o] = 0.f; aB[o] = be1[o0 + o]; }
    for (int k = 0; k < 64; ++k) {
      const float hv = sH[rl][k];
      const float4 g0 = *(const float4*)&We1[k * 64 + o0];
      const float4 g1 = *(const float4*)&We1[k * 64 + o0 + 4];
      const float4 b0 = *(const float4*)&We1[(64 + k) * 64 + o0];
      const float4 b1 = *(const float4*)&We1[(64 + k) * 64 + o0 + 4];
      aG[0] = fmaf(hv, g0.x, aG[0]); aG[1] = fmaf(hv, g0.y, aG[1]);
      aG[2] = fmaf(hv, g0.z, aG[2]); aG[3] = fmaf(hv, g0.w, aG[3]);
      aG[4] = fmaf(hv, g1.x, aG[4]); aG[5] = fmaf(hv, g1.y, aG[5]);
      aG[6] = fmaf(hv, g1.z, aG[6]); aG[7] = fmaf(hv, g1.w, aG[7]);
      aB[0] = fmaf(hv, b0.x, aB[0]); aB[1] = fmaf(hv, b0.y, aB[1]);
      aB[2] = fmaf(hv, b0.z, aB[2]); aB[3] = fmaf(hv, b0.w, aB[3]);
      aB[4] = fmaf(hv, b1.x, aB[4]); aB[5] = fmaf(hv, b1.y, aB[5]);
      aB[6] = fmaf(hv, b1.z, aB[6]); aB[7] = fmaf(hv, b1.w, aB[7]);
    }
    const size_t base = (size_t)(r0 + rl) * 64 + o0;
    *(float4*)&G[base]        = make_float4(aG[0], aG[1], aG[2], aG[3]);
    *(float4*)&G[base + 4]    = make_float4(aG[4], aG[5], aG[6], aG[7]);
    *(float4*)&Base[base]     = make_float4(aB[0], aB[1], aB[2], aB[3]);
    *(float4*)&Base[base + 4] = make_float4(aB[4], aB[5], aB[6], aB[7]);
  } else {
    for (int idx = tid; idx < 10240; idx += 256) {
      float w; unsigned short *ph, *pl; int pos;
      if (idx < 4096)      { const int o = idx >> 6,          k = idx & 63;
                             w = We2[k * 64 + o]; ph = w2h; pl = w2l; pos = o * 64 + k; }
      else if (idx < 8192) { const int t = idx - 4096, o = t >> 6, k = t & 63;
                             w = Wc1[k * 64 + o]; ph = w3h; pl = w3l; pos = o * 64 + k; }
      else                 { const int t = idx - 8192, c = t >> 6, k = t & 63;
                             w = Wc2[k * 32 + c]; ph = w4h; pl = w4l; pos = c * 64 + k; }
      const unsigned short hi = f2bf(w);
      const unsigned short lo = f2bf(w - bf2f(hi));
      ph[pos] = hi; pl[pos] = lo;
    }
  }
}

// pack 4 f32 -> 4 bf16 (hi only), store to LDS at element index a
__device__ __forceinline__ void pack_store4(unsigned short* sAh, int a,
                                            float v0, float v1, float v2, float v3) {
  *(uint2*)&sAh[a] = make_uint2(cvt_pk_bf16(v0, v1), cvt_pk_bf16(v2, v3));
}

// ---------------- main kernel ----------------
// Acts stored bf16 (hi only); weights 2-term hi/lo split. Products:
// (w_hi + w_lo) * a_hi  -> 2 MFMA per k-slice.
// __launch_bounds__(256, 6): VGPR cap 85 (usage 80, no spill), 6 blocks/CU
// (LDS 20.5KB x 6 = 123KB <= 160KB). Deeper residency to hide the 4-barrier
// per-tile chain. R4 lesson: (256,4)+lo-split spilled (VGPR 64, WRITE 55MB);
// watch WRITE_SIZE stays ~592KB.
__global__ __launch_bounds__(256, 6)
void sake_mfma(const float* __restrict__ h, const float* __restrict__ x,
               const float* __restrict__ mask,
               const float* __restrict__ We1, const float* __restrict__ be2,
               const float* __restrict__ bc1, const float* __restrict__ bc2,
               const float* __restrict__ Wp1, const float* __restrict__ bp1,
               const float* __restrict__ Wp2, const float* __restrict__ bp2,
               const float* __restrict__ Wn1, const float* __restrict__ bn1,
               const float* __restrict__ Wn2, const float* __restrict__ bn2,
               const float* __restrict__ G, const float* __restrict__ Base,
               const unsigned short* __restrict__ w2h, const unsigned short* __restrict__ w2l,
               const unsigned short* __restrict__ w3h, const unsigned short* __restrict__ w3l,
               const unsigned short* __restrict__ w4h, const unsigned short* __restrict__ w4l,
               float* __restrict__ out)
{
  __shared__ unsigned short sAh[2 * 4096];   // act bf16, ping/pong [j][k] swizzled
  __shared__ float sVecM[64][4];             // vec*mask per j
  __shared__ float sMask[64];
  __shared__ float sBase[64], sW1n[64], sHi[64], sXi[4];
  __shared__ float sHe[64], sCombP[4 * 48], sCN[32], sTmp[64], sHcomb[64];

  const int tid  = (int)threadIdx.x;
  const int blk  = (int)blockIdx.x;
  const int b    = blk >> 9;
  const int i    = blk & 511;
  const int lane = tid & 63;
  const int wid  = tid >> 6;
  const int l15  = lane & 15;
  const int lg   = lane >> 4;            // 0..3
  const int mb   = wid * 16;             // feat block (L2/C1)
  const int mb2  = (wid >> 1) * 16;      // coeff block (C2)

  if (tid < 64) {
    sBase[tid] = Base[((size_t)(b * NN + i)) * 64 + tid];
    sW1n[tid]  = We1[128 * 64 + tid];
    sHi[tid]   = h[((size_t)(b * NN + i)) * 64 + tid];
  }
  if (tid < 3) sXi[tid] = x[((size_t)(b * NN + i)) * 3 + tid];

  short8v w2hF[2], w2lF[2], w3hF[2], w3lF[2], w4hF[2], w4lF[2];
  #pragma unroll
  for (int ks = 0; ks < 2; ++ks) {
    const int ko = ks * 32 + lg * 8;
    w2hF[ks] = *(const short8v*)&w2h[(mb  + l15) * 64 + ko];
    w2lF[ks] = *(const short8v*)&w2l[(mb  + l15) * 64 + ko];
    w3hF[ks] = *(const short8v*)&w3h[(mb  + l15) * 64 + ko];
    w3lF[ks] = *(const short8v*)&w3l[(mb  + l15) * 64 + ko];
    w4hF[ks] = *(const short8v*)&w4h[(mb2 + l15) * 64 + ko];
    w4lF[ks] = *(const short8v*)&w4l[(mb2 + l15) * 64 + ko];
  }
  float be2v[4], bc1v[4], bc2v[4];
  #pragma unroll
  for (int r = 0; r < 4; ++r) {
    be2v[r] = be2[mb  + lg * 4 + r];
    bc1v[r] = bc1[mb  + lg * 4 + r];
    bc2v[r] = bc2[mb2 + lg * 4 + r];
  }

  float heAcc[4] = {0.f, 0.f, 0.f, 0.f};
  float cAcc[4][3] = {};

  for (int jt = 0; jt < 8; ++jt) {
    const int jb = jt * 64;
    __syncthreads();   // A: prev tile's C2 reads + sVecM reads done

    if (tid < 64) {    // geometry for this tile
      const int j = tid;
      const size_t xo = ((size_t)(b * NN + jb + j)) * 3;
      const float dx = x[xo + 0] - sXi[0];
      const float dy = x[xo + 1] - sXi[1];
      const float dz = x[xo + 2] - sXi[2];
      const float n2 = dx * dx + dy * dy + dz * dz;
      const float inv = __builtin_amdgcn_rcpf(n2 * n2 + 1e-10f);
      const float m = mask[((size_t)(b * NN + i)) * NN + jb + j];
      sVecM[j][0] = dx * inv * m; sVecM[j][1] = dy * inv * m; sVecM[j][2] = dz * inv * m;
      sMask[j] = m;
    }

    // ---- L1 elementwise: act1 = silu(G + Base + n2*We1n) -> buf0 ----
    {
      const int j = l15 + wid * 16;          // tile-local j (4 threads per j)
      const int jglob = jb + j;
      const size_t xo = ((size_t)(b * NN + jglob)) * 3;
      const float dx = x[xo + 0] - sXi[0];
      const float dy = x[xo + 1] - sXi[1];
      const float dz = x[xo + 2] - sXi[2];
      const float n2 = dx * dx + dy * dy + dz * dz;
      #pragma unroll
      for (int kk = 0; kk < 4; ++kk) {
        const int kb = lg * 16 + kk * 4;
        const float4 g4 = *(const float4*)&G[((size_t)(b * NN + jglob)) * 64 + kb];
        const float4 bs = *(const float4*)&sBase[kb];
        const float4 wn = *(const float4*)&sW1n[kb];
        const float v0 = silu_f(g4.x + bs.x + n2 * wn.x);
        const float v1 = silu_f(g4.y + bs.y + n2 * wn.y);
        const float v2 = silu_f(g4.z + bs.z + n2 * wn.z);
        const float v3 = silu_f(g4.w + bs.w + n2 * wn.w);
        pack_store4(sAh, AIDX(j, kb), v0, v1, v2, v3);
      }
    }
    __syncthreads();   // B: buf0 + geometry ready

    // ---- L2: act2 = silu(act1 @ We2 + be2) -> buf1 ; h_e accum ----
    #pragma unroll
    for (int nf = 0; nf < 4; ++nf) {
      const int jn = nf * 16 + l15;
      f32x4 acc = { be2v[0], be2v[1], be2v[2], be2v[3] };
      #pragma unroll
      for (int ks = 0; ks < 2; ++ks) {
        const int kb = ks * 32 + lg * 8;
        const short8v bh = *(const short8v*)&sAh[AIDX(jn, kb)];
        acc = __builtin_amdgcn_mfma_f32_16x16x32_bf16(w2hF[ks], bh, acc, 0, 0, 0);
        acc = __builtin_amdgcn_mfma_f32_16x16x32_bf16(w2lF[ks], bh, acc, 0, 0, 0);
      }
      const float m = sMask[jn];
      float v[4];
      #pragma unroll
      for (int r = 0; r < 4; ++r) { v[r] = silu_f(acc[r]); heAcc[r] = fmaf(v[r], m, heAcc[r]); }
      pack_store4(sAh, 4096 + AIDX(jn, mb + lg * 4), v[0], v[1], v[2], v[3]);
    }
    __syncthreads();   // C: buf1 ready (all buf0 reads done)

    // ---- C1: act3 = silu(act2 @ Wc1 + bc1) -> buf0 ----
    #pragma unroll
    for (int nf = 0; nf < 4; ++nf) {
      const int jn = nf * 16 + l15;
      f32x4 acc = { bc1v[0], bc1v[1], bc1v[2], bc1v[3] };
      #pragma unroll
      for (int ks = 0; ks < 2; ++ks) {
        const int kb = ks * 32 + lg * 8;
        const short8v bh = *(const short8v*)&sAh[4096 + AIDX(jn, kb)];
        acc = __builtin_amdgcn_mfma_f32_16x16x32_bf16(w3hF[ks], bh, acc, 0, 0, 0);
        acc = __builtin_amdgcn_mfma_f32_16x16x32_bf16(w3lF[ks], bh, acc, 0, 0, 0);
      }
      float v[4];
      #pragma unroll
      for (int r = 0; r < 4; ++r) v[r] = silu_f(acc[r]);
      pack_store4(sAh, AIDX(jn, mb + lg * 4), v[0], v[1], v[2], v[3]);
    }
    __syncthreads();   // D: buf0(act3) ready

    // ---- C2: coeff = act3 @ Wc2 + bc2 ; comb accumulation ----
    #pragma unroll
    for (int nf = 0; nf < 2; ++nf) {
      const int jn = (wid & 1) * 32 + nf * 16 + l15;
      f32x4 acc = { bc2v[0], bc2v[1], bc2v[2], bc2v[3] };
      #pragma unroll
      for (int ks = 0; ks < 2; ++ks) {
        const int kb = ks * 32 + lg * 8;
        const short8v bh = *(const short8v*)&sAh[AIDX(jn, kb)];
        acc = __builtin_amdgcn_mfma_f32_16x16x32_bf16(w4hF[ks], bh, acc, 0, 0, 0);
        acc = __builtin_amdgcn_mfma_f32_16x16x32_bf16(w4lF[ks], bh, acc, 0, 0, 0);
      }
      const float vm0 = sVecM[jn][0], vm1 = sVecM[jn][1], vm2 = sVecM[jn][2];
      #pragma unroll
      for (int r = 0; r < 4; ++r) {
        cAcc[r][0] = fmaf(acc[r], vm0, cAcc[r][0]);
        cAcc[r][1] = fmaf(acc[r], vm1, cAcc[r][1]);
        cAcc[r][2] = fmaf(acc[r], vm2, cAcc[r][2]);
      }
    }
  }

  // -------- reductions --------
  #pragma unroll
  for (int r = 0; r < 4; ++r) {
    float s = heAcc[r];
    s += __shfl_xor(s, 1); s += __shfl_xor(s, 2); s += __shfl_xor(s, 4); s += __shfl_xor(s, 8);
    if (l15 == 0) sHe[mb + lg * 4 + r] = s;
  }
  #pragma unroll
  for (int r = 0; r < 4; ++r)
    #pragma unroll
    for (int d = 0; d < 3; ++d) {
      float s = cAcc[r][d];
      s += __shfl_xor(s, 1); s += __shfl_xor(s, 2); s += __shfl_xor(s, 4); s += __shfl_xor(s, 8);
      if (l15 == 0) sCombP[wid * 48 + (lg * 4 + r) * 3 + d] = s;
    }
  __syncthreads();
  if (tid < 32) {
    const int c = tid, w0 = (c >> 4) * 2, cl = c & 15;
    const float s0 = sCombP[w0 * 48 + cl * 3 + 0] + sCombP[(w0 + 1) * 48 + cl * 3 + 0];
    const float s1 = sCombP[w0 * 48 + cl * 3 + 1] + sCombP[(w0 + 1) * 48 + cl * 3 + 1];
    const float s2 = sCombP[w0 * 48 + cl * 3 + 2] + sCombP[(w0 + 1) * 48 + cl * 3 + 2];
    sCN[c] = s0 * s0 + s1 * s1 + s2 * s2;
  }
  __syncthreads();

  // -------- epilogue MLPs (fp32, tiny) --------
  if (tid < 64) {
    float s = bp1[tid];
    #pragma unroll 8
    for (int c = 0; c < 32; ++c) s = fmaf(sCN[c], Wp1[c * 64 + tid], s);
    sTmp[tid] = silu_f(s);
  }
  __syncthreads();
  if (tid < 64) {
    float s = bp2[tid];
    #pragma unroll 16
    for (int k = 0; k < 64; ++k) s = fmaf(sTmp[k], Wp2[k * 64 + tid], s);
    sHcomb[tid] = s;
  }
  __syncthreads();
  if (tid < 64) {
    float s = bn1[tid];
    #pragma unroll 16
    for (int m = 0; m < 64; ++m) s = fmaf(sHi[m],    Wn1[m * 64 + tid],         s);
    #pragma unroll 16
    for (int m = 0; m < 64; ++m) s = fmaf(sHe[m],    Wn1[(64 + m) * 64 + tid],  s);
    #pragma unroll 16
    for (int m = 0; m < 64; ++m) s = fmaf(sHcomb[m], Wn1[(128 + m) * 64 + tid], s);
    sTmp[tid] = silu_f(s);
  }
  __syncthreads();
  if (tid < 64) {
    float s = bn2[tid];
    #pragma unroll 16
    for (int k = 0; k < 64; ++k) s = fmaf(sTmp[k], Wn2[k * 64 + tid], s);
    out[((size_t)(b * NN + i)) * 64 + tid] = sHi[tid] + s;
  } else if (tid < 67) {
    const int d = tid - 64;
    out[(size_t)BB * NN * FF + ((size_t)(b * NN + i)) * 3 + d] = x[((size_t)(b * NN + i)) * 3 + d];
  }
}

extern "C" void kernel_launch(void* const* d_in, const int* in_sizes, int n_in,
                              void* d_out, int out_size, void* d_ws, size_t ws_size,
                              hipStream_t stream) {
  const float* h    = (const float*)d_in[0];
  const float* x    = (const float*)d_in[1];
  const float* mask = (const float*)d_in[2];
  const float* We1  = (const float*)d_in[3];
  const float* be1  = (const float*)d_in[4];
  const float* We2  = (const float*)d_in[5];
  const float* be2  = (const float*)d_in[6];
  const float* Wc1  = (const float*)d_in[7];
  const float* bc1  = (const float*)d_in[8];
  const float* Wc2  = (const float*)d_in[9];
  const float* bc2  = (const float*)d_in[10];
  const float* Wp1  = (const float*)d_in[11];
  const float* bp1  = (const float*)d_in[12];
  const float* Wp2  = (const float*)d_in[13];
  const float* bp2  = (const float*)d_in[14];
  const float* Wn1  = (const float*)d_in[15];
  const float* bn1  = (const float*)d_in[16];
  const float* Wn2  = (const float*)d_in[17];
  const float* bn2  = (const float*)d_in[18];
  float* out = (float*)d_out;

  float* G    = (float*)d_ws;                       // 2048*64 f32
  float* Base = G + 2048 * 64;                      // 2048*64 f32
  unsigned short* w2h = (unsigned short*)(Base + 2048 * 64);
  unsigned short* w2l = w2h + 4096;
  unsigned short* w3h = w2l + 4096;
  unsigned short* w3l = w3h + 4096;
  unsigned short* w4h = w3l + 4096;
  unsigned short* w4l = w4h + 2048;

  hipLaunchKernelGGL(sake_prep, dim3(65), dim3(256), 0, stream,
                     h, We1, be1, We2, Wc1, Wc2, G, Base,
                     w2h, w2l, w3h, w3l, w4h, w4l);
  hipLaunchKernelGGL(sake_mfma, dim3(BB * NN), dim3(256), 0, stream,
                     h, x, mask, We1, be2, bc1, bc2,
                     Wp1, bp1, Wp2, bp2, Wn1, bn1, Wn2, bn2,
                     G, Base, w2h, w2l, w3h, w3l, w4h, w4l, out);
}

// Round 7
// 172.549 us; speedup vs baseline: 1.5882x; 1.5882x over previous
//
#include <hip/hip_runtime.h>

#define BB 4
#define NN 512
#define FF 64

typedef __attribute__((ext_vector_type(8))) short short8v;   // 8 bf16 = 4 VGPR
typedef __attribute__((ext_vector_type(4))) float f32x4;

__device__ __forceinline__ float silu_f(float v) {
  return v * __builtin_amdgcn_rcpf(1.0f + __expf(-v));
}
__device__ __forceinline__ unsigned short f2bf(float f) {
  unsigned int u = __float_as_uint(f);
  unsigned int r = (u + 0x7FFFu + ((u >> 16) & 1u)) >> 16;   // RNE (prep kernel only)
  return (unsigned short)r;
}
__device__ __forceinline__ float bf2f(unsigned short s) {
  return __uint_as_float(((unsigned int)s) << 16);
}
// packed f32x2 -> bf16x2 (RNE), low16 = a
__device__ __forceinline__ unsigned cvt_pk_bf16(float a, float b) {
  unsigned r;
  asm("v_cvt_pk_bf16_f32 %0, %1, %2" : "=v"(r) : "v"(a), "v"(b));
  return r;
}

// act LDS addressing: [j][k] bf16 rows of 128B, 16B slots XOR-swizzled by j. j in 0..127.
#define AIDX(j, k) ((((j) << 6)) | (((((k) >> 3) ^ ((j) & 7))) << 3) | ((k) & 7))

// ---------------- prep kernel (unchanged from R5) ----------------
__global__ void sake_prep(const float* __restrict__ h, const float* __restrict__ We1,
                          const float* __restrict__ be1, const float* __restrict__ We2,
                          const float* __restrict__ Wc1, const float* __restrict__ Wc2,
                          float* __restrict__ G, float* __restrict__ Base,
                          unsigned short* __restrict__ w2h, unsigned short* __restrict__ w2l,
                          unsigned short* __restrict__ w3h, unsigned short* __restrict__ w3l,
                          unsigned short* __restrict__ w4h, unsigned short* __restrict__ w4l)
{
  const int wg = (int)blockIdx.x, tid = (int)threadIdx.x;
  if (wg < 64) {
    __shared__ float sH[32][64];
    const int r0 = wg * 32;
    for (int idx = tid; idx < 2048; idx += 256) sH[idx >> 6][idx & 63] = h[r0 * 64 + idx];
    __syncthreads();
    const int rl = tid >> 3;
    const int o0 = (tid & 7) * 8;
    float aG[8], aB[8];
    #pragma unroll
    for (int o = 0; o < 8; ++o) { aG[o] = 0.f; aB[o] = be1[o0 + o]; }
    for (int k = 0; k < 64; ++k) {
      const float hv = sH[rl][k];
      const float4 g0 = *(const float4*)&We1[k * 64 + o0];
      const float4 g1 = *(const float4*)&We1[k * 64 + o0 + 4];
      const float4 b0 = *(const float4*)&We1[(64 + k) * 64 + o0];
      const float4 b1 = *(const float4*)&We1[(64 + k) * 64 + o0 + 4];
      aG[0] = fmaf(hv, g0.x, aG[0]); aG[1] = fmaf(hv, g0.y, aG[1]);
      aG[2] = fmaf(hv, g0.z, aG[2]); aG[3] = fmaf(hv, g0.w, aG[3]);
      aG[4] = fmaf(hv, g1.x, aG[4]); aG[5] = fmaf(hv, g1.y, aG[5]);
      aG[6] = fmaf(hv, g1.z, aG[6]); aG[7] = fmaf(hv, g1.w, aG[7]);
      aB[0] = fmaf(hv, b0.x, aB[0]); aB[1] = fmaf(hv, b0.y, aB[1]);
      aB[2] = fmaf(hv, b0.z, aB[2]); aB[3] = fmaf(hv, b0.w, aB[3]);
      aB[4] = fmaf(hv, b1.x, aB[4]); aB[5] = fmaf(hv, b1.y, aB[5]);
      aB[6] = fmaf(hv, b1.z, aB[6]); aB[7] = fmaf(hv, b1.w, aB[7]);
    }
    const size_t base = (size_t)(r0 + rl) * 64 + o0;
    *(float4*)&G[base]        = make_float4(aG[0], aG[1], aG[2], aG[3]);
    *(float4*)&G[base + 4]    = make_float4(aG[4], aG[5], aG[6], aG[7]);
    *(float4*)&Base[base]     = make_float4(aB[0], aB[1], aB[2], aB[3]);
    *(float4*)&Base[base + 4] = make_float4(aB[4], aB[5], aB[6], aB[7]);
  } else {
    for (int idx = tid; idx < 10240; idx += 256) {
      float w; unsigned short *ph, *pl; int pos;
      if (idx < 4096)      { const int o = idx >> 6,          k = idx & 63;
                             w = We2[k * 64 + o]; ph = w2h; pl = w2l; pos = o * 64 + k; }
      else if (idx < 8192) { const int t = idx - 4096, o = t >> 6, k = t & 63;
                             w = Wc1[k * 64 + o]; ph = w3h; pl = w3l; pos = o * 64 + k; }
      else                 { const int t = idx - 8192, c = t >> 6, k = t & 63;
                             w = Wc2[k * 32 + c]; ph = w4h; pl = w4l; pos = c * 64 + k; }
      const unsigned short hi = f2bf(w);
      const unsigned short lo = f2bf(w - bf2f(hi));
      ph[pos] = hi; pl[pos] = lo;
    }
  }
}

__device__ __forceinline__ void pack_store4(unsigned short* sA, int a,
                                            float v0, float v1, float v2, float v3) {
  *(uint2*)&sA[a] = make_uint2(cvt_pk_bf16(v0, v1), cvt_pk_bf16(v2, v3));
}

// ---------------- main kernel ----------------
// TILE=128 (4 tiles), 3 LDS act buffers A/B/C -> 3 barriers per tile (12 total).
// C2 uses wave-own j's so vec*mask stays in registers (no sVecM race).
// (256,3): VGPR cap ~168; LDS 51.6KB -> 3 blocks/CU. R6 lesson: (256,6) spilled.
__global__ __launch_bounds__(256, 3)
void sake_mfma(const float* __restrict__ h, const float* __restrict__ x,
               const float* __restrict__ mask,
               const float* __restrict__ We1, const float* __restrict__ be2,
               const float* __restrict__ bc1, const float* __restrict__ bc2,
               const float* __restrict__ Wp1, const float* __restrict__ bp1,
               const float* __restrict__ Wp2, const float* __restrict__ bp2,
               const float* __restrict__ Wn1, const float* __restrict__ bn1,
               const float* __restrict__ Wn2, const float* __restrict__ bn2,
               const float* __restrict__ G, const float* __restrict__ Base,
               const unsigned short* __restrict__ w2h, const unsigned short* __restrict__ w2l,
               const unsigned short* __restrict__ w3h, const unsigned short* __restrict__ w3l,
               const unsigned short* __restrict__ w4h, const unsigned short* __restrict__ w4l,
               float* __restrict__ out)
{
  __shared__ unsigned short sAct[3 * 8192];  // bufA | bufB | bufC, [j 0..127][k 0..63] swizzled
  __shared__ float sMaskL[128];
  __shared__ float sBase[64], sW1n[64], sHi[64];
  __shared__ float sB2[64], sB3[64], sB4[32];
  __shared__ float sHe[64], sCombP[4][96], sCN[32], sTmp[64], sHcomb[64];

  const int tid  = (int)threadIdx.x;
  const int blk  = (int)blockIdx.x;
  const int b    = blk >> 9;
  const int i    = blk & 511;
  const int lane = tid & 63;
  const int wid  = tid >> 6;
  const int l15  = lane & 15;
  const int lg   = lane >> 4;            // 0..3
  const int mb   = wid * 16;             // feat block (L2/C1)

  if (tid < 64) {
    sBase[tid] = Base[((size_t)(b * NN + i)) * 64 + tid];
    sW1n[tid]  = We1[128 * 64 + tid];
    sHi[tid]   = h[((size_t)(b * NN + i)) * 64 + tid];
    sB2[tid]   = be2[tid];
    sB3[tid]   = bc1[tid];
  }
  if (tid < 32) sB4[tid] = bc2[tid];
  const float xi0 = x[((size_t)(b * NN + i)) * 3 + 0];
  const float xi1 = x[((size_t)(b * NN + i)) * 3 + 1];
  const float xi2 = x[((size_t)(b * NN + i)) * 3 + 2];

  // weight A-frags in registers
  short8v w2hF[2], w2lF[2], w3hF[2], w3lF[2], w4hF[2][2], w4lF[2][2];
  #pragma unroll
  for (int ks = 0; ks < 2; ++ks) {
    const int ko = ks * 32 + lg * 8;
    w2hF[ks] = *(const short8v*)&w2h[(mb + l15) * 64 + ko];
    w2lF[ks] = *(const short8v*)&w2l[(mb + l15) * 64 + ko];
    w3hF[ks] = *(const short8v*)&w3h[(mb + l15) * 64 + ko];
    w3lF[ks] = *(const short8v*)&w3l[(mb + l15) * 64 + ko];
    #pragma unroll
    for (int m2 = 0; m2 < 2; ++m2) {
      w4hF[m2][ks] = *(const short8v*)&w4h[(m2 * 16 + l15) * 64 + ko];
      w4lF[m2][ks] = *(const short8v*)&w4l[(m2 * 16 + l15) * 64 + ko];
    }
  }

  float heAcc[4] = {0.f, 0.f, 0.f, 0.f};
  float cAcc[2][4][3] = {};

  __syncthreads();   // prologue staging complete

  for (int jt = 0; jt < 4; ++jt) {
    const int jb = jt * 128;

    // ---- geometry (in-lane, registers) + L1 -> bufA ----
    float vmr[2][3], n2v[2];
    #pragma unroll
    for (int jj = 0; jj < 2; ++jj) {
      const int j = jb + jj * 64 + wid * 16 + l15;   // 0..511
      const size_t xo = ((size_t)(b * NN + j)) * 3;
      const float dx = x[xo + 0] - xi0;
      const float dy = x[xo + 1] - xi1;
      const float dz = x[xo + 2] - xi2;
      const float n2 = dx * dx + dy * dy + dz * dz;
      const float inv = __builtin_amdgcn_rcpf(n2 * n2 + 1e-10f);
      const float m = mask[((size_t)(b * NN + i)) * NN + j];
      vmr[jj][0] = dx * inv * m; vmr[jj][1] = dy * inv * m; vmr[jj][2] = dz * inv * m;
      n2v[jj] = n2;
      if (lg == 0) sMaskL[jj * 64 + wid * 16 + l15] = m;
    }
    #pragma unroll
    for (int kk = 0; kk < 4; ++kk) {
      const int kb = lg * 16 + kk * 4;
      const float4 bs = *(const float4*)&sBase[kb];
      const float4 wn = *(const float4*)&sW1n[kb];
      #pragma unroll
      for (int jj = 0; jj < 2; ++jj) {
        const int jloc = jj * 64 + wid * 16 + l15;
        const float4 g4 = *(const float4*)&G[((size_t)(b * NN + jb + jloc)) * 64 + kb];
        const float n2 = n2v[jj];
        const float v0 = silu_f(g4.x + bs.x + n2 * wn.x);
        const float v1 = silu_f(g4.y + bs.y + n2 * wn.y);
        const float v2 = silu_f(g4.z + bs.z + n2 * wn.z);
        const float v3 = silu_f(g4.w + bs.w + n2 * wn.w);
        pack_store4(sAct, AIDX(jloc, kb), v0, v1, v2, v3);
      }
    }
    __syncthreads();   // B: bufA + sMaskL ready

    // ---- L2: bufA -> bufB ; h_e accum ----
    {
      const f32x4 bias = *(const f32x4*)&sB2[mb + lg * 4];
      #pragma unroll
      for (int nf = 0; nf < 8; ++nf) {
        const int jn = nf * 16 + l15;
        f32x4 acc = bias;
        #pragma unroll
        for (int ks = 0; ks < 2; ++ks) {
          const short8v bh = *(const short8v*)&sAct[AIDX(jn, ks * 32 + lg * 8)];
          acc = __builtin_amdgcn_mfma_f32_16x16x32_bf16(w2hF[ks], bh, acc, 0, 0, 0);
          acc = __builtin_amdgcn_mfma_f32_16x16x32_bf16(w2lF[ks], bh, acc, 0, 0, 0);
        }
        const float m = sMaskL[jn];
        float v[4];
        #pragma unroll
        for (int r = 0; r < 4; ++r) { v[r] = silu_f(acc[r]); heAcc[r] = fmaf(v[r], m, heAcc[r]); }
        pack_store4(sAct, 8192 + AIDX(jn, mb + lg * 4), v[0], v[1], v[2], v[3]);
      }
    }
    __syncthreads();   // C: bufB ready

    // ---- C1: bufB -> bufC ----
    {
      const f32x4 bias = *(const f32x4*)&sB3[mb + lg * 4];
      #pragma unroll
      for (int nf = 0; nf < 8; ++nf) {
        const int jn = nf * 16 + l15;
        f32x4 acc = bias;
        #pragma unroll
        for (int ks = 0; ks < 2; ++ks) {
          const short8v bh = *(const short8v*)&sAct[8192 + AIDX(jn, ks * 32 + lg * 8)];
          acc = __builtin_amdgcn_mfma_f32_16x16x32_bf16(w3hF[ks], bh, acc, 0, 0, 0);
          acc = __builtin_amdgcn_mfma_f32_16x16x32_bf16(w3lF[ks], bh, acc, 0, 0, 0);
        }
        float v[4];
        #pragma unroll
        for (int r = 0; r < 4; ++r) v[r] = silu_f(acc[r]);
        pack_store4(sAct, 16384 + AIDX(jn, mb + lg * 4), v[0], v[1], v[2], v[3]);
      }
    }
    __syncthreads();   // D: bufC ready

    // ---- C2: bufC (wave-own j's, both c-blocks) ; comb accum (vm in regs) ----
    #pragma unroll
    for (int jj = 0; jj < 2; ++jj) {
      const int jloc = jj * 64 + wid * 16 + l15;
      const short8v bh0 = *(const short8v*)&sAct[16384 + AIDX(jloc, lg * 8)];
      const short8v bh1 = *(const short8v*)&sAct[16384 + AIDX(jloc, 32 + lg * 8)];
      #pragma unroll
      for (int m2 = 0; m2 < 2; ++m2) {
        f32x4 acc = *(const f32x4*)&sB4[m2 * 16 + lg * 4];
        acc = __builtin_amdgcn_mfma_f32_16x16x32_bf16(w4hF[m2][0], bh0, acc, 0, 0, 0);
        acc = __builtin_amdgcn_mfma_f32_16x16x32_bf16(w4lF[m2][0], bh0, acc, 0, 0, 0);
        acc = __builtin_amdgcn_mfma_f32_16x16x32_bf16(w4hF[m2][1], bh1, acc, 0, 0, 0);
        acc = __builtin_amdgcn_mfma_f32_16x16x32_bf16(w4lF[m2][1], bh1, acc, 0, 0, 0);
        #pragma unroll
        for (int r = 0; r < 4; ++r) {
          cAcc[m2][r][0] = fmaf(acc[r], vmr[jj][0], cAcc[m2][r][0]);
          cAcc[m2][r][1] = fmaf(acc[r], vmr[jj][1], cAcc[m2][r][1]);
          cAcc[m2][r][2] = fmaf(acc[r], vmr[jj][2], cAcc[m2][r][2]);
        }
      }
    }
    // no barrier: bufA reuse is 2 barriers away (safe)
  }

  // -------- reductions --------
  #pragma unroll
  for (int r = 0; r < 4; ++r) {
    float s = heAcc[r];
    s += __shfl_xor(s, 1); s += __shfl_xor(s, 2); s += __shfl_xor(s, 4); s += __shfl_xor(s, 8);
    if (l15 == 0) sHe[mb + lg * 4 + r] = s;
  }
  #pragma unroll
  for (int m2 = 0; m2 < 2; ++m2)
    #pragma unroll
    for (int r = 0; r < 4; ++r)
      #pragma unroll
      for (int d = 0; d < 3; ++d) {
        float s = cAcc[m2][r][d];
        s += __shfl_xor(s, 1); s += __shfl_xor(s, 2); s += __shfl_xor(s, 4); s += __shfl_xor(s, 8);
        if (l15 == 0) sCombP[wid][(m2 * 16 + lg * 4 + r) * 3 + d] = s;
      }
  __syncthreads();
  if (tid < 32) {
    const int c = tid;
    float s0 = 0.f, s1 = 0.f, s2 = 0.f;
    #pragma unroll
    for (int w = 0; w < 4; ++w) {
      s0 += sCombP[w][c * 3 + 0];
      s1 += sCombP[w][c * 3 + 1];
      s2 += sCombP[w][c * 3 + 2];
    }
    sCN[c] = s0 * s0 + s1 * s1 + s2 * s2;
  }
  __syncthreads();

  // -------- epilogue MLPs (fp32, tiny) --------
  if (tid < 64) {
    float s = bp1[tid];
    #pragma unroll 8
    for (int c = 0; c < 32; ++c) s = fmaf(sCN[c], Wp1[c * 64 + tid], s);
    sTmp[tid] = silu_f(s);
  }
  __syncthreads();
  if (tid < 64) {
    float s = bp2[tid];
    #pragma unroll 16
    for (int k = 0; k < 64; ++k) s = fmaf(sTmp[k], Wp2[k * 64 + tid], s);
    sHcomb[tid] = s;
  }
  __syncthreads();
  if (tid < 64) {
    float s = bn1[tid];
    #pragma unroll 16
    for (int m = 0; m < 64; ++m) s = fmaf(sHi[m],    Wn1[m * 64 + tid],         s);
    #pragma unroll 16
    for (int m = 0; m < 64; ++m) s = fmaf(sHe[m],    Wn1[(64 + m) * 64 + tid],  s);
    #pragma unroll 16
    for (int m = 0; m < 64; ++m) s = fmaf(sHcomb[m], Wn1[(128 + m) * 64 + tid], s);
    sTmp[tid] = silu_f(s);
  }
  __syncthreads();
  if (tid < 64) {
    float s = bn2[tid];
    #pragma unroll 16
    for (int k = 0; k < 64; ++k) s = fmaf(sTmp[k], Wn2[k * 64 + tid], s);
    out[((size_t)(b * NN + i)) * 64 + tid] = sHi[tid] + s;
  } else if (tid < 67) {
    const int d = tid - 64;
    out[(size_t)BB * NN * FF + ((size_t)(b * NN + i)) * 3 + d] = x[((size_t)(b * NN + i)) * 3 + d];
  }
}

extern "C" void kernel_launch(void* const* d_in, const int* in_sizes, int n_in,
                              void* d_out, int out_size, void* d_ws, size_t ws_size,
                              hipStream_t stream) {
  const float* h    = (const float*)d_in[0];
  const float* x    = (const float*)d_in[1];
  const float* mask = (const float*)d_in[2];
  const float* We1  = (const float*)d_in[3];
  const float* be1  = (const float*)d_in[4];
  const float* We2  = (const float*)d_in[5];
  const float* be2  = (const float*)d_in[6];
  const float* Wc1  = (const float*)d_in[7];
  const float* bc1  = (const float*)d_in[8];
  const float* Wc2  = (const float*)d_in[9];
  const float* bc2  = (const float*)d_in[10];
  const float* Wp1  = (const float*)d_in[11];
  const float* bp1  = (const float*)d_in[12];
  const float* Wp2  = (const float*)d_in[13];
  const float* bp2  = (const float*)d_in[14];
  const float* Wn1  = (const float*)d_in[15];
  const float* bn1  = (const float*)d_in[16];
  const float* Wn2  = (const float*)d_in[17];
  const float* bn2  = (const float*)d_in[18];
  float* out = (float*)d_out;

  float* G    = (float*)d_ws;                       // 2048*64 f32
  float* Base = G + 2048 * 64;                      // 2048*64 f32
  unsigned short* w2h = (unsigned short*)(Base + 2048 * 64);
  unsigned short* w2l = w2h + 4096;
  unsigned short* w3h = w2l + 4096;
  unsigned short* w3l = w3h + 4096;
  unsigned short* w4h = w3l + 4096;
  unsigned short* w4l = w4h + 2048;

  hipLaunchKernelGGL(sake_prep, dim3(65), dim3(256), 0, stream,
                     h, We1, be1, We2, Wc1, Wc2, G, Base,
                     w2h, w2l, w3h, w3l, w4h, w4l);
  hipLaunchKernelGGL(sake_mfma, dim3(BB * NN), dim3(256), 0, stream,
                     h, x, mask, We1, be2, bc1, bc2,
                     Wp1, bp1, Wp2, bp2, Wn1, bn1, Wn2, bn2,
                     G, Base, w2h, w2l, w3h, w3l, w4h, w4l, out);
}

// Round 8
// 124.511 us; speedup vs baseline: 2.2009x; 1.3858x over previous
//
#include <hip/hip_runtime.h>

#define BB 4
#define NN 512
#define FF 64

typedef __attribute__((ext_vector_type(8))) short short8v;   // 8 bf16 = 4 VGPR
typedef __attribute__((ext_vector_type(4))) float f32x4;

__device__ __forceinline__ float silu_f(float v) {
  return v * __builtin_amdgcn_rcpf(1.0f + __expf(-v));
}
__device__ __forceinline__ unsigned short f2bf(float f) {
  unsigned int u = __float_as_uint(f);
  unsigned int r = (u + 0x7FFFu + ((u >> 16) & 1u)) >> 16;   // RNE (prep kernel only)
  return (unsigned short)r;
}
__device__ __forceinline__ float bf2f(unsigned short s) {
  return __uint_as_float(((unsigned int)s) << 16);
}
// packed f32x2 -> bf16x2 (RNE), low16 = a
__device__ __forceinline__ unsigned cvt_pk_bf16(float a, float b) {
  unsigned r;
  asm("v_cvt_pk_bf16_f32 %0, %1, %2" : "=v"(r) : "v"(a), "v"(b));
  return r;
}

// act LDS addressing: [j][k] bf16 rows of 128B, 16B slots XOR-swizzled by j. j in 0..127.
#define AIDX(j, k) ((((j) << 6)) | (((((k) >> 3) ^ ((j) & 7))) << 3) | ((k) & 7))

// ---------------- prep kernel (unchanged) ----------------
__global__ void sake_prep(const float* __restrict__ h, const float* __restrict__ We1,
                          const float* __restrict__ be1, const float* __restrict__ We2,
                          const float* __restrict__ Wc1, const float* __restrict__ Wc2,
                          float* __restrict__ G, float* __restrict__ Base,
                          unsigned short* __restrict__ w2h, unsigned short* __restrict__ w2l,
                          unsigned short* __restrict__ w3h, unsigned short* __restrict__ w3l,
                          unsigned short* __restrict__ w4h, unsigned short* __restrict__ w4l)
{
  const int wg = (int)blockIdx.x, tid = (int)threadIdx.x;
  if (wg < 64) {
    __shared__ float sH[32][64];
    const int r0 = wg * 32;
    for (int idx = tid; idx < 2048; idx += 256) sH[idx >> 6][idx & 63] = h[r0 * 64 + idx];
    __syncthreads();
    const int rl = tid >> 3;
    const int o0 = (tid & 7) * 8;
    float aG[8], aB[8];
    #pragma unroll
    for (int o = 0; o < 8; ++o) { aG[o] = 0.f; aB[o] = be1[o0 + o]; }
    for (int k = 0; k < 64; ++k) {
      const float hv = sH[rl][k];
      const float4 g0 = *(const float4*)&We1[k * 64 + o0];
      const float4 g1 = *(const float4*)&We1[k * 64 + o0 + 4];
      const float4 b0 = *(const float4*)&We1[(64 + k) * 64 + o0];
      const float4 b1 = *(const float4*)&We1[(64 + k) * 64 + o0 + 4];
      aG[0] = fmaf(hv, g0.x, aG[0]); aG[1] = fmaf(hv, g0.y, aG[1]);
      aG[2] = fmaf(hv, g0.z, aG[2]); aG[3] = fmaf(hv, g0.w, aG[3]);
      aG[4] = fmaf(hv, g1.x, aG[4]); aG[5] = fmaf(hv, g1.y, aG[5]);
      aG[6] = fmaf(hv, g1.z, aG[6]); aG[7] = fmaf(hv, g1.w, aG[7]);
      aB[0] = fmaf(hv, b0.x, aB[0]); aB[1] = fmaf(hv, b0.y, aB[1]);
      aB[2] = fmaf(hv, b0.z, aB[2]); aB[3] = fmaf(hv, b0.w, aB[3]);
      aB[4] = fmaf(hv, b1.x, aB[4]); aB[5] = fmaf(hv, b1.y, aB[5]);
      aB[6] = fmaf(hv, b1.z, aB[6]); aB[7] = fmaf(hv, b1.w, aB[7]);
    }
    const size_t base = (size_t)(r0 + rl) * 64 + o0;
    *(float4*)&G[base]        = make_float4(aG[0], aG[1], aG[2], aG[3]);
    *(float4*)&G[base + 4]    = make_float4(aG[4], aG[5], aG[6], aG[7]);
    *(float4*)&Base[base]     = make_float4(aB[0], aB[1], aB[2], aB[3]);
    *(float4*)&Base[base + 4] = make_float4(aB[4], aB[5], aB[6], aB[7]);
  } else {
    for (int idx = tid; idx < 10240; idx += 256) {
      float w; unsigned short *ph, *pl; int pos;
      if (idx < 4096)      { const int o = idx >> 6,          k = idx & 63;
                             w = We2[k * 64 + o]; ph = w2h; pl = w2l; pos = o * 64 + k; }
      else if (idx < 8192) { const int t = idx - 4096, o = t >> 6, k = t & 63;
                             w = Wc1[k * 64 + o]; ph = w3h; pl = w3l; pos = o * 64 + k; }
      else                 { const int t = idx - 8192, c = t >> 6, k = t & 63;
                             w = Wc2[k * 32 + c]; ph = w4h; pl = w4l; pos = c * 64 + k; }
      const unsigned short hi = f2bf(w);
      const unsigned short lo = f2bf(w - bf2f(hi));
      ph[pos] = hi; pl[pos] = lo;
    }
  }
}

__device__ __forceinline__ void pack_store4(unsigned short* sA, int a,
                                            float v0, float v1, float v2, float v3) {
  *(uint2*)&sA[a] = make_uint2(cvt_pk_bf16(v0, v1), cvt_pk_bf16(v2, v3));
}

// ---------------- main kernel ----------------
// TILE=128 (4 tiles), 3 LDS act buffers -> 3 barriers/tile (12 total).
// Register-light C2 (R7 lesson: persistent regs > compiler's 84 alloc -> spills):
//   one c-block per wave (w4 = 16 VGPR), vec*mask RECOMPUTED inside C2 phase
//   (x/mask re-loads are L1-hot) so no register crosses a barrier.
__global__ __launch_bounds__(256, 3)
void sake_mfma(const float* __restrict__ h, const float* __restrict__ x,
               const float* __restrict__ mask,
               const float* __restrict__ We1, const float* __restrict__ be2,
               const float* __restrict__ bc1, const float* __restrict__ bc2,
               const float* __restrict__ Wp1, const float* __restrict__ bp1,
               const float* __restrict__ Wp2, const float* __restrict__ bp2,
               const float* __restrict__ Wn1, const float* __restrict__ bn1,
               const float* __restrict__ Wn2, const float* __restrict__ bn2,
               const float* __restrict__ G, const float* __restrict__ Base,
               const unsigned short* __restrict__ w2h, const unsigned short* __restrict__ w2l,
               const unsigned short* __restrict__ w3h, const unsigned short* __restrict__ w3l,
               const unsigned short* __restrict__ w4h, const unsigned short* __restrict__ w4l,
               float* __restrict__ out)
{
  __shared__ unsigned short sAct[3 * 8192];  // bufA | bufB | bufC, [j 0..127][k 0..63] swizzled
  __shared__ float sMaskL[128];
  __shared__ float sBase[64], sW1n[64], sHi[64];
  __shared__ float sB2[64], sB3[64], sB4[32];
  __shared__ float sHe[64], sCombP[4][48], sCN[32], sTmp[64], sHcomb[64];

  const int tid  = (int)threadIdx.x;
  const int blk  = (int)blockIdx.x;
  const int b    = blk >> 9;
  const int i    = blk & 511;
  const int lane = tid & 63;
  const int wid  = tid >> 6;
  const int l15  = lane & 15;
  const int lg   = lane >> 4;            // 0..3
  const int mb   = wid * 16;             // feat block (L2/C1)
  const int m2   = wid & 1;              // c-block (C2)
  const int jh   = (wid >> 1) * 16;      // C2 j sub-block

  const size_t mrow = ((size_t)(b * NN + i)) * NN;

  if (tid < 64) {
    sBase[tid] = Base[((size_t)(b * NN + i)) * 64 + tid];
    sW1n[tid]  = We1[128 * 64 + tid];
    sHi[tid]   = h[((size_t)(b * NN + i)) * 64 + tid];
    sB2[tid]   = be2[tid];
    sB3[tid]   = bc1[tid];
  }
  if (tid < 32) sB4[tid] = bc2[tid];
  const float xi0 = x[((size_t)(b * NN + i)) * 3 + 0];
  const float xi1 = x[((size_t)(b * NN + i)) * 3 + 1];
  const float xi2 = x[((size_t)(b * NN + i)) * 3 + 2];

  // weight A-frags in registers: w2/w3 full (16 feats per wave), w4 one c-block
  short8v w2hF[2], w2lF[2], w3hF[2], w3lF[2], w4hF[2], w4lF[2];
  #pragma unroll
  for (int ks = 0; ks < 2; ++ks) {
    const int ko = ks * 32 + lg * 8;
    w2hF[ks] = *(const short8v*)&w2h[(mb + l15) * 64 + ko];
    w2lF[ks] = *(const short8v*)&w2l[(mb + l15) * 64 + ko];
    w3hF[ks] = *(const short8v*)&w3h[(mb + l15) * 64 + ko];
    w3lF[ks] = *(const short8v*)&w3l[(mb + l15) * 64 + ko];
    w4hF[ks] = *(const short8v*)&w4h[(m2 * 16 + l15) * 64 + ko];
    w4lF[ks] = *(const short8v*)&w4l[(m2 * 16 + l15) * 64 + ko];
  }

  float heAcc[4] = {0.f, 0.f, 0.f, 0.f};
  float cAcc[4][3] = {};

  __syncthreads();   // prologue staging complete

  for (int jt = 0; jt < 4; ++jt) {
    const int jb = jt * 128;

    // ---- L1: act1 = silu(G + Base + n2*We1n) -> bufA ; stash mask ----
    #pragma unroll
    for (int jj = 0; jj < 2; ++jj) {
      const int jloc = jj * 64 + wid * 16 + l15;
      const int j = jb + jloc;
      const size_t xo = ((size_t)(b * NN + j)) * 3;
      const float dx = x[xo + 0] - xi0;
      const float dy = x[xo + 1] - xi1;
      const float dz = x[xo + 2] - xi2;
      const float n2 = dx * dx + dy * dy + dz * dz;
      if (lg == 0) sMaskL[jloc] = mask[mrow + j];
      #pragma unroll
      for (int kk = 0; kk < 4; ++kk) {
        const int kb = lg * 16 + kk * 4;
        const float4 g4 = *(const float4*)&G[((size_t)(b * NN + j)) * 64 + kb];
        const float4 bs = *(const float4*)&sBase[kb];
        const float4 wn = *(const float4*)&sW1n[kb];
        const float v0 = silu_f(g4.x + bs.x + n2 * wn.x);
        const float v1 = silu_f(g4.y + bs.y + n2 * wn.y);
        const float v2 = silu_f(g4.z + bs.z + n2 * wn.z);
        const float v3 = silu_f(g4.w + bs.w + n2 * wn.w);
        pack_store4(sAct, AIDX(jloc, kb), v0, v1, v2, v3);
      }
    }
    __syncthreads();   // B: bufA + sMaskL ready

    // ---- L2: bufA -> bufB ; h_e accum ----
    {
      const f32x4 bias = *(const f32x4*)&sB2[mb + lg * 4];
      #pragma unroll
      for (int nf = 0; nf < 8; ++nf) {
        const int jn = nf * 16 + l15;
        f32x4 acc = bias;
        #pragma unroll
        for (int ks = 0; ks < 2; ++ks) {
          const short8v bh = *(const short8v*)&sAct[AIDX(jn, ks * 32 + lg * 8)];
          acc = __builtin_amdgcn_mfma_f32_16x16x32_bf16(w2hF[ks], bh, acc, 0, 0, 0);
          acc = __builtin_amdgcn_mfma_f32_16x16x32_bf16(w2lF[ks], bh, acc, 0, 0, 0);
        }
        const float m = sMaskL[jn];
        float v[4];
        #pragma unroll
        for (int r = 0; r < 4; ++r) { v[r] = silu_f(acc[r]); heAcc[r] = fmaf(v[r], m, heAcc[r]); }
        pack_store4(sAct, 8192 + AIDX(jn, mb + lg * 4), v[0], v[1], v[2], v[3]);
      }
    }
    __syncthreads();   // C: bufB ready

    // ---- C1: bufB -> bufC ----
    {
      const f32x4 bias = *(const f32x4*)&sB3[mb + lg * 4];
      #pragma unroll
      for (int nf = 0; nf < 8; ++nf) {
        const int jn = nf * 16 + l15;
        f32x4 acc = bias;
        #pragma unroll
        for (int ks = 0; ks < 2; ++ks) {
          const short8v bh = *(const short8v*)&sAct[8192 + AIDX(jn, ks * 32 + lg * 8)];
          acc = __builtin_amdgcn_mfma_f32_16x16x32_bf16(w3hF[ks], bh, acc, 0, 0, 0);
          acc = __builtin_amdgcn_mfma_f32_16x16x32_bf16(w3lF[ks], bh, acc, 0, 0, 0);
        }
        float v[4];
        #pragma unroll
        for (int r = 0; r < 4; ++r) v[r] = silu_f(acc[r]);
        pack_store4(sAct, 16384 + AIDX(jn, mb + lg * 4), v[0], v[1], v[2], v[3]);
      }
    }
    __syncthreads();   // D: bufC ready

    // ---- C2: bufC ; vec*mask recomputed IN-PHASE (no cross-barrier regs) ----
    {
      const f32x4 bias = *(const f32x4*)&sB4[m2 * 16 + lg * 4];
      #pragma unroll
      for (int jj = 0; jj < 4; ++jj) {
        const int jloc = jj * 32 + jh + l15;   // 0..127, all 8 j-blocks over 4 waves
        const int j = jb + jloc;
        const size_t xo = ((size_t)(b * NN + j)) * 3;
        const float dx = x[xo + 0] - xi0;
        const float dy = x[xo + 1] - xi1;
        const float dz = x[xo + 2] - xi2;
        const float n2 = dx * dx + dy * dy + dz * dz;
        const float inv = __builtin_amdgcn_rcpf(n2 * n2 + 1e-10f);
        const float m = mask[mrow + j];
        const float vm0 = dx * inv * m, vm1 = dy * inv * m, vm2 = dz * inv * m;
        const short8v bh0 = *(const short8v*)&sAct[16384 + AIDX(jloc, lg * 8)];
        const short8v bh1 = *(const short8v*)&sAct[16384 + AIDX(jloc, 32 + lg * 8)];
        f32x4 acc = bias;
        acc = __builtin_amdgcn_mfma_f32_16x16x32_bf16(w4hF[0], bh0, acc, 0, 0, 0);
        acc = __builtin_amdgcn_mfma_f32_16x16x32_bf16(w4lF[0], bh0, acc, 0, 0, 0);
        acc = __builtin_amdgcn_mfma_f32_16x16x32_bf16(w4hF[1], bh1, acc, 0, 0, 0);
        acc = __builtin_amdgcn_mfma_f32_16x16x32_bf16(w4lF[1], bh1, acc, 0, 0, 0);
        #pragma unroll
        for (int r = 0; r < 4; ++r) {
          cAcc[r][0] = fmaf(acc[r], vm0, cAcc[r][0]);
          cAcc[r][1] = fmaf(acc[r], vm1, cAcc[r][1]);
          cAcc[r][2] = fmaf(acc[r], vm2, cAcc[r][2]);
        }
      }
    }
    // no barrier: each buffer's write is >=2 barriers after its last read
  }

  // -------- reductions --------
  #pragma unroll
  for (int r = 0; r < 4; ++r) {
    float s = heAcc[r];
    s += __shfl_xor(s, 1); s += __shfl_xor(s, 2); s += __shfl_xor(s, 4); s += __shfl_xor(s, 8);
    if (l15 == 0) sHe[mb + lg * 4 + r] = s;
  }
  #pragma unroll
  for (int r = 0; r < 4; ++r)
    #pragma unroll
    for (int d = 0; d < 3; ++d) {
      float s = cAcc[r][d];
      s += __shfl_xor(s, 1); s += __shfl_xor(s, 2); s += __shfl_xor(s, 4); s += __shfl_xor(s, 8);
      if (l15 == 0) sCombP[wid][(lg * 4 + r) * 3 + d] = s;
    }
  __syncthreads();
  if (tid < 32) {
    const int c = tid, cm2 = c >> 4, cl = c & 15;
    const float s0 = sCombP[cm2][cl * 3 + 0] + sCombP[cm2 + 2][cl * 3 + 0];
    const float s1 = sCombP[cm2][cl * 3 + 1] + sCombP[cm2 + 2][cl * 3 + 1];
    const float s2 = sCombP[cm2][cl * 3 + 2] + sCombP[cm2 + 2][cl * 3 + 2];
    sCN[c] = s0 * s0 + s1 * s1 + s2 * s2;
  }
  __syncthreads();

  // -------- epilogue MLPs (fp32, tiny) --------
  if (tid < 64) {
    float s = bp1[tid];
    #pragma unroll 8
    for (int c = 0; c < 32; ++c) s = fmaf(sCN[c], Wp1[c * 64 + tid], s);
    sTmp[tid] = silu_f(s);
  }
  __syncthreads();
  if (tid < 64) {
    float s = bp2[tid];
    #pragma unroll 16
    for (int k = 0; k < 64; ++k) s = fmaf(sTmp[k], Wp2[k * 64 + tid], s);
    sHcomb[tid] = s;
  }
  __syncthreads();
  if (tid < 64) {
    float s = bn1[tid];
    #pragma unroll 16
    for (int m = 0; m < 64; ++m) s = fmaf(sHi[m],    Wn1[m * 64 + tid],         s);
    #pragma unroll 16
    for (int m = 0; m < 64; ++m) s = fmaf(sHe[m],    Wn1[(64 + m) * 64 + tid],  s);
    #pragma unroll 16
    for (int m = 0; m < 64; ++m) s = fmaf(sHcomb[m], Wn1[(128 + m) * 64 + tid], s);
    sTmp[tid] = silu_f(s);
  }
  __syncthreads();
  if (tid < 64) {
    float s = bn2[tid];
    #pragma unroll 16
    for (int k = 0; k < 64; ++k) s = fmaf(sTmp[k], Wn2[k * 64 + tid], s);
    out[((size_t)(b * NN + i)) * 64 + tid] = sHi[tid] + s;
  } else if (tid < 67) {
    const int d = tid - 64;
    out[(size_t)BB * NN * FF + ((size_t)(b * NN + i)) * 3 + d] = x[((size_t)(b * NN + i)) * 3 + d];
  }
}

extern "C" void kernel_launch(void* const* d_in, const int* in_sizes, int n_in,
                              void* d_out, int out_size, void* d_ws, size_t ws_size,
                              hipStream_t stream) {
  const float* h    = (const float*)d_in[0];
  const float* x    = (const float*)d_in[1];
  const float* mask = (const float*)d_in[2];
  const float* We1  = (const float*)d_in[3];
  const float* be1  = (const float*)d_in[4];
  const float* We2  = (const float*)d_in[5];
  const float* be2  = (const float*)d_in[6];
  const float* Wc1  = (const float*)d_in[7];
  const float* bc1  = (const float*)d_in[8];
  const float* Wc2  = (const float*)d_in[9];
  const float* bc2  = (const float*)d_in[10];
  const float* Wp1  = (const float*)d_in[11];
  const float* bp1  = (const float*)d_in[12];
  const float* Wp2  = (const float*)d_in[13];
  const float* bp2  = (const float*)d_in[14];
  const float* Wn1  = (const float*)d_in[15];
  const float* bn1  = (const float*)d_in[16];
  const float* Wn2  = (const float*)d_in[17];
  const float* bn2  = (const float*)d_in[18];
  float* out = (float*)d_out;

  float* G    = (float*)d_ws;                       // 2048*64 f32
  float* Base = G + 2048 * 64;                      // 2048*64 f32
  unsigned short* w2h = (unsigned short*)(Base + 2048 * 64);
  unsigned short* w2l = w2h + 4096;
  unsigned short* w3h = w2l + 4096;
  unsigned short* w3l = w3h + 4096;
  unsigned short* w4h = w3l + 4096;
  unsigned short* w4l = w4h + 2048;

  hipLaunchKernelGGL(sake_prep, dim3(65), dim3(256), 0, stream,
                     h, We1, be1, We2, Wc1, Wc2, G, Base,
                     w2h, w2l, w3h, w3l, w4h, w4l);
  hipLaunchKernelGGL(sake_mfma, dim3(BB * NN), dim3(256), 0, stream,
                     h, x, mask, We1, be2, bc1, bc2,
                     Wp1, bp1, Wp2, bp2, Wn1, bn1, Wn2, bn2,
                     G, Base, w2h, w2l, w3h, w3l, w4h, w4l, out);
}